// Round 5
// baseline (744.232 us; speedup 1.0000x reference)
//
#include <hip/hip_runtime.h>
#include <cstdint>
#include <cstddef>

#define NN 50000
#define EE 1600000
#define D  64
#define DE 16

__device__ __forceinline__ float bf2f(unsigned short u) {
    return __uint_as_float(((unsigned)u) << 16);
}
__device__ __forceinline__ unsigned short f2bf(float f) {
    unsigned u = __float_as_uint(f);
    unsigned r = u + 0x7FFFu + ((u >> 16) & 1u);   // RNE
    return (unsigned short)(r >> 16);
}

// ---------------- tiny precompute: wae[k] = sum_c We[k][c]*ae[c], both layers
__global__ void k_wae(const float* We1, const float* ae1,
                      const float* We2, const float* ae2,
                      float* wae /*32 floats*/) {
    int t = threadIdx.x;
    if (t < 32) {
        const float* We = (t < 16) ? We1 : We2;
        const float* ae = (t < 16) ? ae1 : ae2;
        int k = t & 15;
        float acc = 0.f;
        for (int c = 0; c < D; c++) acc += We[k * D + c] * ae[c];
        wae[t] = acc;
    }
}

// ---------------- histogram of dst
__global__ __launch_bounds__(256) void k_hist(const int* dst, int* counts) {
    int e = blockIdx.x * 256 + threadIdx.x;
    if (e < EE) atomicAdd(&counts[dst[e]], 1);
}

// ---------------- 3-kernel exclusive scan over counts (chunks of 256)
__global__ __launch_bounds__(256) void k_scanA(const int* counts, int* bsum) {
    __shared__ int tmp[256];
    int t = threadIdx.x, i = blockIdx.x * 256 + t;
    tmp[t] = (i < NN) ? counts[i] : 0;
    __syncthreads();
    for (int off = 128; off; off >>= 1) {
        if (t < off) tmp[t] += tmp[t + off];
        __syncthreads();
    }
    if (t == 0) bsum[blockIdx.x] = tmp[0];
}

__global__ __launch_bounds__(256) void k_scanB(int* bsum, int nchunks) {
    __shared__ int tmp[256];
    int t = threadIdx.x;
    int v = (t < nchunks) ? bsum[t] : 0;
    tmp[t] = v; __syncthreads();
    for (int off = 1; off < 256; off <<= 1) {
        int x = (t >= off) ? tmp[t - off] : 0;
        __syncthreads();
        tmp[t] += x;
        __syncthreads();
    }
    if (t < nchunks) bsum[t] = tmp[t] - v;   // exclusive
}

__global__ __launch_bounds__(256) void k_scanC(const int* counts, const int* bsumex,
                                               int* offsets, int* cursor) {
    __shared__ int tmp[256];
    int t = threadIdx.x, i = blockIdx.x * 256 + t;
    int v = (i < NN) ? counts[i] : 0;
    tmp[t] = v; __syncthreads();
    for (int off = 1; off < 256; off <<= 1) {
        int x = (t >= off) ? tmp[t - off] : 0;
        __syncthreads();
        tmp[t] += x;
        __syncthreads();
    }
    int excl = tmp[t] - v + bsumex[blockIdx.x];
    if (i < NN) { offsets[i] = excl; cursor[i] = excl; }
}

// ---------------- scatter edges into dst-sorted AoS records {src, eid, ee1, ee2}
// single 16-B scattered write per edge (was 4x4-B SoA writes -> ~4x sector amplification)
__global__ __launch_bounds__(256) void k_scatter(const int* src, const int* dst,
                                                 const float* ea, const float* wae,
                                                 int* cursor, int4* recs) {
    int e = blockIdx.x * 256 + threadIdx.x;
    if (e >= EE) return;
    int d = dst[e];
    const float4* rp = (const float4*)(ea + (size_t)e * DE);
    float4 q0 = rp[0], q1 = rp[1], q2 = rp[2], q3 = rp[3];
    float ev[16] = {q0.x, q0.y, q0.z, q0.w, q1.x, q1.y, q1.z, q1.w,
                    q2.x, q2.y, q2.z, q2.w, q3.x, q3.y, q3.z, q3.w};
    float e1 = 0.f, e2 = 0.f;
    #pragma unroll
    for (int j = 0; j < 16; j++) {
        e1 += ev[j] * wae[j];
        e2 += ev[j] * wae[16 + j];
    }
    int pos = atomicAdd(&cursor[d], 1);
    recs[pos] = make_int4(src[e], e, __float_as_int(e1), __float_as_int(e2));
}

// ---------------- per-layer: h = x@W, hs = h@a_s, hd = h@a_d
// W column in registers (64 VGPR/lane), x row via wave-uniform loads -> zero LDS traffic.
// IN_BF16: layer2 reads the bf16 intermediate (in-place safe: full row read before write).
template<int IN_BF16>
__global__ __launch_bounds__(256) void k_gemm(const void* xin, const float* W,
                                              const float* a_s, const float* a_d,
                                              unsigned short* h, float* hs, float* hd) {
    int t = threadIdx.x, lane = t & 63;
    int wid0 = blockIdx.x * 4 + (t >> 6);        // 4096 waves total
    float Wcol[64];
    #pragma unroll
    for (int k = 0; k < 64; k++) Wcol[k] = W[k * 64 + lane];
    float asl = a_s[lane], adl = a_d[lane];
    for (int n0 = wid0; n0 < NN; n0 += 4096) {
        int n = __builtin_amdgcn_readfirstlane(n0);   // wave-uniform row address
        float acc = 0.f;
        if (IN_BF16) {
            const uint4* xr = (const uint4*)((const unsigned short*)xin + (size_t)n * 64);
            #pragma unroll
            for (int q = 0; q < 8; q++) {
                uint4 u = xr[q];
                unsigned uu[4] = {u.x, u.y, u.z, u.w};
                #pragma unroll
                for (int j = 0; j < 4; j++) {
                    acc += bf2f((unsigned short)(uu[j] & 0xFFFFu)) * Wcol[q * 8 + 2 * j];
                    acc += bf2f((unsigned short)(uu[j] >> 16))     * Wcol[q * 8 + 2 * j + 1];
                }
            }
        } else {
            const float4* xr = (const float4*)((const float*)xin + (size_t)n * 64);
            #pragma unroll
            for (int q = 0; q < 16; q++) {
                float4 u = xr[q];
                acc += u.x * Wcol[4 * q]     + u.y * Wcol[4 * q + 1]
                     + u.z * Wcol[4 * q + 2] + u.w * Wcol[4 * q + 3];
            }
        }
        h[(size_t)n * 64 + lane] = f2bf(acc);
        float ps = acc * asl, pd = acc * adl;
        #pragma unroll
        for (int off = 32; off; off >>= 1) {
            ps += __shfl_xor(ps, off);
            pd += __shfl_xor(pd, off);
        }
        if (lane == 0) { hs[n] = ps; hd[n] = pd; }
    }
}

// ---------------- fused per-node GAT: online-softmax, channel-max aggregate, bias+act
// wave = one node. pass2: 4 groups x 16 lanes, one edge/group/iter, 4 ch/lane,
// 1-deep software pipeline: prefetch next {rec, ea row, h row, hs} while computing current.
template<int L2>   // L2: selects ee field; fp32 output
__global__ __launch_bounds__(256) void k_gat(const int4* recs, const int* offsets, const int* counts,
                                             const float* hs, const float* hd,
                                             const unsigned short* h, const float* ea,
                                             const float* We, const float* b, void* outv) {
    int t = threadIdx.x, lane = t & 63, wv = t >> 6;
    int g = lane >> 4, cl = lane & 15;

    // register-resident We[k][4cl .. 4cl+3]
    float4 WelR[16];
    #pragma unroll
    for (int k = 0; k < 16; k++) WelR[k] = *(const float4*)(We + k * 64 + 4 * cl);

    int d = blockIdx.x * 4 + wv;           // grid is exactly NN/4
    int start = offsets[d];
    int deg = counts[d];

    if (deg == 0) {                        // isfinite -> 0, then bias + act
        if (g == 0) {
            float4 bl = *(const float4*)(b + 4 * cl);
            float o0 = (bl.x >= 0.f) ? bl.x : 0.01f * bl.x;
            float o1 = (bl.y >= 0.f) ? bl.y : 0.01f * bl.y;
            float o2 = (bl.z >= 0.f) ? bl.z : 0.01f * bl.z;
            float o3 = (bl.w >= 0.f) ? bl.w : 0.01f * bl.w;
            size_t oidx = (size_t)d * D + 4 * cl;
            if (L2) *(float4*)((float*)outv + oidx) = make_float4(o0, o1, o2, o3);
            else {
                ushort4 ov = {f2bf(o0), f2bf(o1), f2bf(o2), f2bf(o3)};
                *(ushort4*)((unsigned short*)outv + oidx) = ov;
            }
        }
        return;
    }

    float hdv = hd[d];

    // pass 1: online softmax over logits (lane = edge), streaming AoS recs
    float m = -__builtin_inff();
    float s = 0.f;
    for (int i = lane; i < deg; i += 64) {
        int4 r = recs[start + i];
        float ee = __int_as_float(L2 ? r.w : r.z);
        float lg = hs[r.x] + hdv + ee;
        lg = (lg >= 0.f) ? lg : 0.2f * lg;
        float mn = fmaxf(m, lg);
        s = ((m == mn) ? s : s * __expf(m - mn)) + __expf(lg - mn);
        m = mn;
    }
    #pragma unroll
    for (int off = 32; off; off >>= 1) {
        float m2 = __shfl_xor(m, off);
        float s2 = __shfl_xor(s, off);
        float mn = fmaxf(m, m2);
        float sa = (m == mn) ? s : s * __expf(m - mn);
        float sb = (m2 == mn) ? s2 : s2 * __expf(m2 - mn);
        s = sa + sb;
        m = mn;
    }
    float invs = 1.0f / fmaxf(s, 1e-16f);

    // pass 2, pipelined (deg >= 1 guaranteed here)
    int iters = (deg + 3) >> 2;
    int4 rec = recs[start + min(g, deg - 1)];
    const float4* ep = (const float4*)(ea + (size_t)rec.y * DE);
    float4 A0 = ep[0], A1 = ep[1], A2 = ep[2], A3 = ep[3];
    ushort4 HV = *(const ushort4*)(h + (size_t)rec.x * D + 4 * cl);
    float HS = hs[rec.x];

    float a0 = -__builtin_inff(), a1 = a0, a2 = a0, a3 = a0;
    for (int i = 0; i < iters; i++) {
        // prefetch next stage (clamped index keeps it in-bounds; last prefetch is a dummy)
        int jn = min((i + 1) * 4 + g, deg - 1);
        int4 recn = recs[start + jn];
        const float4* epn = (const float4*)(ea + (size_t)recn.y * DE);
        float4 B0 = epn[0], B1 = epn[1], B2 = epn[2], B3 = epn[3];
        ushort4 HVn = *(const ushort4*)(h + (size_t)recn.x * D + 4 * cl);
        float HSn = hs[recn.x];

        // compute current stage
        bool valid = (i * 4 + g) < deg;
        float ee = __int_as_float(L2 ? rec.w : rec.z);
        float lg = HS + hdv + ee;
        lg = (lg >= 0.f) ? lg : 0.2f * lg;
        float att = __expf(lg - m) * invs;

        float ear[16] = {A0.x, A0.y, A0.z, A0.w, A1.x, A1.y, A1.z, A1.w,
                         A2.x, A2.y, A2.z, A2.w, A3.x, A3.y, A3.z, A3.w};
        float e0 = 0.f, e1 = 0.f, e2 = 0.f, e3 = 0.f;
        #pragma unroll
        for (int k = 0; k < 16; k++) {
            e0 += ear[k] * WelR[k].x;
            e1 += ear[k] * WelR[k].y;
            e2 += ear[k] * WelR[k].z;
            e3 += ear[k] * WelR[k].w;
        }
        float v0 = (bf2f(HV.x) + e0) * att;
        float v1 = (bf2f(HV.y) + e1) * att;
        float v2 = (bf2f(HV.z) + e2) * att;
        float v3 = (bf2f(HV.w) + e3) * att;
        if (!valid) { v0 = v1 = v2 = v3 = -__builtin_inff(); }
        a0 = fmaxf(a0, v0); a1 = fmaxf(a1, v1);
        a2 = fmaxf(a2, v2); a3 = fmaxf(a3, v3);

        // rotate pipeline
        rec = recn; A0 = B0; A1 = B1; A2 = B2; A3 = B3; HV = HVn; HS = HSn;
    }
    // combine the 4 groups (xor lanes 16, 32)
    #pragma unroll
    for (int off = 16; off <= 32; off <<= 1) {
        a0 = fmaxf(a0, __shfl_xor(a0, off));
        a1 = fmaxf(a1, __shfl_xor(a1, off));
        a2 = fmaxf(a2, __shfl_xor(a2, off));
        a3 = fmaxf(a3, __shfl_xor(a3, off));
    }

    if (g == 0) {
        float4 bl = *(const float4*)(b + 4 * cl);
        float o0 = a0 + bl.x, o1 = a1 + bl.y, o2 = a2 + bl.z, o3 = a3 + bl.w;
        o0 = (o0 >= 0.f) ? o0 : 0.01f * o0;
        o1 = (o1 >= 0.f) ? o1 : 0.01f * o1;
        o2 = (o2 >= 0.f) ? o2 : 0.01f * o2;
        o3 = (o3 >= 0.f) ? o3 : 0.01f * o3;
        size_t oidx = (size_t)d * D + 4 * cl;
        if (L2) {
            *(float4*)((float*)outv + oidx) = make_float4(o0, o1, o2, o3);
        } else {
            ushort4 ov = {f2bf(o0), f2bf(o1), f2bf(o2), f2bf(o3)};
            *(ushort4*)((unsigned short*)outv + oidx) = ov;
        }
    }
}

extern "C" void kernel_launch(void* const* d_in, const int* in_sizes, int n_in,
                              void* d_out, int out_size, void* d_ws, size_t ws_size,
                              hipStream_t stream) {
    // reference dtypes are all float32 (+ int32 edge_index)
    const float* X   = (const float*)d_in[0];
    const int*   eix = (const int*)d_in[1];
    const float* ea  = (const float*)d_in[2];
    const float* W1  = (const float*)d_in[3];
    const float* We1 = (const float*)d_in[4];
    const float* as1 = (const float*)d_in[5];
    const float* ad1 = (const float*)d_in[6];
    const float* ae1 = (const float*)d_in[7];
    const float* b1  = (const float*)d_in[8];
    const float* W2  = (const float*)d_in[9];
    const float* We2 = (const float*)d_in[10];
    const float* as2 = (const float*)d_in[11];
    const float* ad2 = (const float*)d_in[12];
    const float* ae2 = (const float*)d_in[13];
    const float* b2  = (const float*)d_in[14];

    const int* src = eix;
    const int* dst = eix + EE;

    // workspace carve — total ~39.4 MB
    char* w = (char*)d_ws;
    int4* recs = (int4*)w;               w += (size_t)EE * 16;         // 25.6 MB
    unsigned short* hA = (unsigned short*)w; w += (size_t)NN * D * 2;  // 6.4 MB (h1)
    unsigned short* hB = (unsigned short*)w; w += (size_t)NN * D * 2;  // 6.4 MB (c1 -> h2 in-place)
    float* hs = (float*)w;               w += (size_t)NN * 4;
    float* hd = (float*)w;               w += (size_t)NN * 4;
    int* counts = (int*)w;               w += (size_t)NN * 4;
    int* offsets = (int*)w;              w += (size_t)NN * 4;
    int* cursor = (int*)w;               w += (size_t)NN * 4;
    int* bsum = (int*)w;                 w += 256 * 4;
    float* wae = (float*)w;              w += 32 * 4;

    const int nchunks = (NN + 255) / 256;   // 196

    hipMemsetAsync(counts, 0, (size_t)NN * 4, stream);
    k_wae<<<1, 64, 0, stream>>>(We1, ae1, We2, ae2, wae);
    k_hist<<<EE / 256, 256, 0, stream>>>(dst, counts);
    k_scanA<<<nchunks, 256, 0, stream>>>(counts, bsum);
    k_scanB<<<1, 256, 0, stream>>>(bsum, nchunks);
    k_scanC<<<nchunks, 256, 0, stream>>>(counts, bsum, offsets, cursor);
    k_scatter<<<EE / 256, 256, 0, stream>>>(src, dst, ea, wae, cursor, recs);

    // layer 1
    k_gemm<0><<<1024, 256, 0, stream>>>(X, W1, as1, ad1, hA, hs, hd);
    k_gat<0><<<NN / 4, 256, 0, stream>>>(recs, offsets, counts, hs, hd, hA, ea, We1, b1, hB);
    // layer 2
    k_gemm<1><<<1024, 256, 0, stream>>>(hB, W2, as2, ad2, hB, hs, hd);   // in-place
    k_gat<1><<<NN / 4, 256, 0, stream>>>(recs, offsets, counts, hs, hd, hB, ea, We2, b2,
                                         (float*)d_out);
}

// Round 6
// 688.933 us; speedup vs baseline: 1.0803x; 1.0803x over previous
//
#include <hip/hip_runtime.h>
#include <cstdint>
#include <cstddef>

#define NN 50000
#define EE 1600000
#define D  64
#define DE 16

typedef __attribute__((ext_vector_type(2))) float vf2;

__device__ __forceinline__ float bf2f(unsigned short u) {
    return __uint_as_float(((unsigned)u) << 16);
}
__device__ __forceinline__ unsigned short f2bf(float f) {
    unsigned u = __float_as_uint(f);
    unsigned r = u + 0x7FFFu + ((u >> 16) & 1u);   // RNE
    return (unsigned short)(r >> 16);
}
__device__ __forceinline__ vf2 vmax2(vf2 a, vf2 b) {
    vf2 r; r.x = fmaxf(a.x, b.x); r.y = fmaxf(a.y, b.y); return r;
}

// ---------------- histogram of dst
__global__ __launch_bounds__(256) void k_hist(const int* dst, int* counts) {
    int e = blockIdx.x * 256 + threadIdx.x;
    if (e < EE) atomicAdd(&counts[dst[e]], 1);
}

// ---------------- 3-kernel exclusive scan over counts (chunks of 256)
__global__ __launch_bounds__(256) void k_scanA(const int* counts, int* bsum) {
    __shared__ int tmp[256];
    int t = threadIdx.x, i = blockIdx.x * 256 + t;
    tmp[t] = (i < NN) ? counts[i] : 0;
    __syncthreads();
    for (int off = 128; off; off >>= 1) {
        if (t < off) tmp[t] += tmp[t + off];
        __syncthreads();
    }
    if (t == 0) bsum[blockIdx.x] = tmp[0];
}

__global__ __launch_bounds__(256) void k_scanB(int* bsum, int nchunks) {
    __shared__ int tmp[256];
    int t = threadIdx.x;
    int v = (t < nchunks) ? bsum[t] : 0;
    tmp[t] = v; __syncthreads();
    for (int off = 1; off < 256; off <<= 1) {
        int x = (t >= off) ? tmp[t - off] : 0;
        __syncthreads();
        tmp[t] += x;
        __syncthreads();
    }
    if (t < nchunks) bsum[t] = tmp[t] - v;   // exclusive
}

__global__ __launch_bounds__(256) void k_scanC(const int* counts, const int* bsumex,
                                               int* offsets, int* cursor) {
    __shared__ int tmp[256];
    int t = threadIdx.x, i = blockIdx.x * 256 + t;
    int v = (i < NN) ? counts[i] : 0;
    tmp[t] = v; __syncthreads();
    for (int off = 1; off < 256; off <<= 1) {
        int x = (t >= off) ? tmp[t - off] : 0;
        __syncthreads();
        tmp[t] += x;
        __syncthreads();
    }
    int excl = tmp[t] - v + bsumex[blockIdx.x];
    if (i < NN) { offsets[i] = excl; cursor[i] = excl; }
}

// ---------------- scatter edges into dst-sorted AoS records {src, eid, ee1, ee2}
// wae = We@ae (both layers) recomputed per block (fused former k_wae dispatch)
__global__ __launch_bounds__(256) void k_scatter(const int* src, const int* dst,
                                                 const float* ea,
                                                 const float* We1, const float* ae1,
                                                 const float* We2, const float* ae2,
                                                 int* cursor, int4* recs) {
    __shared__ float wsh[32];
    int t = threadIdx.x;
    if (t < 32) {
        const float* We = (t < 16) ? We1 : We2;
        const float* ae = (t < 16) ? ae1 : ae2;
        int k = t & 15;
        float acc = 0.f;
        #pragma unroll
        for (int c = 0; c < 64; c++) acc += We[k * 64 + c] * ae[c];
        wsh[t] = acc;
    }
    __syncthreads();
    float w1r[16], w2r[16];
    #pragma unroll
    for (int j = 0; j < 16; j++) { w1r[j] = wsh[j]; w2r[j] = wsh[16 + j]; }

    int e = blockIdx.x * 256 + t;
    if (e >= EE) return;
    int d = dst[e];
    const float4* rp = (const float4*)(ea + (size_t)e * DE);
    float4 q0 = rp[0], q1 = rp[1], q2 = rp[2], q3 = rp[3];
    float ev[16] = {q0.x, q0.y, q0.z, q0.w, q1.x, q1.y, q1.z, q1.w,
                    q2.x, q2.y, q2.z, q2.w, q3.x, q3.y, q3.z, q3.w};
    float e1 = 0.f, e2 = 0.f;
    #pragma unroll
    for (int j = 0; j < 16; j++) {
        e1 += ev[j] * w1r[j];
        e2 += ev[j] * w2r[j];
    }
    int pos = atomicAdd(&cursor[d], 1);
    recs[pos] = make_int4(src[e], e, __float_as_int(e1), __float_as_int(e2));
}

// ---------------- per-layer: h = x@W, hs = h@a_s, hd = h@a_d
// W column in registers (64 VGPR/lane), x row via wave-uniform loads -> zero LDS traffic.
// IN_BF16: layer2 reads the bf16 intermediate (in-place safe: full row read before write).
template<int IN_BF16>
__global__ __launch_bounds__(256) void k_gemm(const void* xin, const float* W,
                                              const float* a_s, const float* a_d,
                                              unsigned short* h, float* hs, float* hd) {
    int t = threadIdx.x, lane = t & 63;
    int wid0 = blockIdx.x * 4 + (t >> 6);        // 4096 waves total
    float Wcol[64];
    #pragma unroll
    for (int k = 0; k < 64; k++) Wcol[k] = W[k * 64 + lane];
    float asl = a_s[lane], adl = a_d[lane];
    for (int n0 = wid0; n0 < NN; n0 += 4096) {
        int n = __builtin_amdgcn_readfirstlane(n0);   // wave-uniform row address
        float acc = 0.f;
        if (IN_BF16) {
            const uint4* xr = (const uint4*)((const unsigned short*)xin + (size_t)n * 64);
            #pragma unroll
            for (int q = 0; q < 8; q++) {
                uint4 u = xr[q];
                unsigned uu[4] = {u.x, u.y, u.z, u.w};
                #pragma unroll
                for (int j = 0; j < 4; j++) {
                    acc += bf2f((unsigned short)(uu[j] & 0xFFFFu)) * Wcol[q * 8 + 2 * j];
                    acc += bf2f((unsigned short)(uu[j] >> 16))     * Wcol[q * 8 + 2 * j + 1];
                }
            }
        } else {
            const float4* xr = (const float4*)((const float*)xin + (size_t)n * 64);
            #pragma unroll
            for (int q = 0; q < 16; q++) {
                float4 u = xr[q];
                acc += u.x * Wcol[4 * q]     + u.y * Wcol[4 * q + 1]
                     + u.z * Wcol[4 * q + 2] + u.w * Wcol[4 * q + 3];
            }
        }
        h[(size_t)n * 64 + lane] = f2bf(acc);
        float ps = acc * asl, pd = acc * adl;
        #pragma unroll
        for (int off = 32; off; off >>= 1) {
            ps += __shfl_xor(ps, off);
            pd += __shfl_xor(pd, off);
        }
        if (lane == 0) { hs[n] = ps; hd[n] = pd; }
    }
}

// ---------------- fused per-node GAT: online-softmax, att cached in LDS,
// channel-max aggregate with packed-f32 math, bias+act.
// wave = one node. pass2: 4 groups x 16 lanes, one edge/group/iter, 4 ch/lane.
#define ATT_CAP 128
template<int L2>   // L2: selects ee field; fp32 output
__global__ __launch_bounds__(256) void k_gat(const int4* recs, const int* offsets, const int* counts,
                                             const float* hs, const float* hd,
                                             const unsigned short* h, const float* ea,
                                             const float* We, const float* b, void* outv) {
    __shared__ float attl[4][ATT_CAP];
    int t = threadIdx.x, lane = t & 63, wv = t >> 6;
    int g = lane >> 4, cl = lane & 15;

    // register-resident We[k][4cl .. 4cl+3], packed as float2 pairs for v_pk_fma_f32
    vf2 W01[16], W23[16];
    #pragma unroll
    for (int k = 0; k < 16; k++) {
        float4 w = *(const float4*)(We + k * 64 + 4 * cl);
        W01[k].x = w.x; W01[k].y = w.y;
        W23[k].x = w.z; W23[k].y = w.w;
    }

    int d = blockIdx.x * 4 + wv;           // grid is exactly NN/4
    int start = offsets[d];
    int deg = counts[d];

    if (deg == 0) {                        // isfinite -> 0, then bias + act
        if (g == 0) {
            float4 bl = *(const float4*)(b + 4 * cl);
            float o0 = (bl.x >= 0.f) ? bl.x : 0.01f * bl.x;
            float o1 = (bl.y >= 0.f) ? bl.y : 0.01f * bl.y;
            float o2 = (bl.z >= 0.f) ? bl.z : 0.01f * bl.z;
            float o3 = (bl.w >= 0.f) ? bl.w : 0.01f * bl.w;
            size_t oidx = (size_t)d * D + 4 * cl;
            if (L2) *(float4*)((float*)outv + oidx) = make_float4(o0, o1, o2, o3);
            else {
                ushort4 ov = {f2bf(o0), f2bf(o1), f2bf(o2), f2bf(o3)};
                *(ushort4*)((unsigned short*)outv + oidx) = ov;
            }
        }
        return;
    }

    float hdv = hd[d];

    // pass 1: online softmax over logits (lane = edge); cache logits in LDS
    float m = -__builtin_inff();
    float s = 0.f;
    for (int i = lane; i < deg; i += 64) {
        int4 r = recs[start + i];
        float ee = __int_as_float(L2 ? r.w : r.z);
        float lg = hs[r.x] + hdv + ee;
        lg = (lg >= 0.f) ? lg : 0.2f * lg;
        if (i < ATT_CAP) attl[wv][i] = lg;
        float mn = fmaxf(m, lg);
        s = ((m == mn) ? s : s * __expf(m - mn)) + __expf(lg - mn);
        m = mn;
    }
    #pragma unroll
    for (int off = 32; off; off >>= 1) {
        float m2 = __shfl_xor(m, off);
        float s2 = __shfl_xor(s, off);
        float mn = fmaxf(m, m2);
        float sa = (m == mn) ? s : s * __expf(m - mn);
        float sb = (m2 == mn) ? s2 : s2 * __expf(m2 - mn);
        s = sa + sb;
        m = mn;
    }
    float invs = 1.0f / fmaxf(s, 1e-16f);

    // fixup: logits -> final attention weights in LDS (same wave: no barrier needed)
    int capdeg = min(deg, ATT_CAP);
    for (int i = lane; i < capdeg; i += 64)
        attl[wv][i] = __expf(attl[wv][i] - m) * invs;

    // pass 2: 4 edges/iter (one per 16-lane group), 4 channels per lane, packed f32
    vf2 ninf2; ninf2.x = -__builtin_inff(); ninf2.y = -__builtin_inff();
    vf2 a01 = ninf2, a23 = ninf2;
    bool cached = (deg <= ATT_CAP);        // wave-uniform
    for (int i = 0; i < deg; i += 4) {
        int j = i + g;
        bool valid = (j < deg);
        int jc = valid ? j : 0;
        int4 r = recs[start + jc];
        float att;
        if (cached) {
            att = attl[wv][jc];            // 16-lane broadcast read
        } else {
            float ee = __int_as_float(L2 ? r.w : r.z);
            float lg = hs[r.x] + hdv + ee;
            lg = (lg >= 0.f) ? lg : 0.2f * lg;
            att = __expf(lg - m) * invs;
        }
        const float4* ep = (const float4*)(ea + (size_t)r.y * DE);
        float4 q0 = ep[0], q1 = ep[1], q2 = ep[2], q3 = ep[3];
        ushort4 hv = *(const ushort4*)(h + (size_t)r.x * D + 4 * cl);

        float ear[16] = {q0.x, q0.y, q0.z, q0.w, q1.x, q1.y, q1.z, q1.w,
                         q2.x, q2.y, q2.z, q2.w, q3.x, q3.y, q3.z, q3.w};
        vf2 e01 = {0.f, 0.f}, e23 = {0.f, 0.f};
        #pragma unroll
        for (int k = 0; k < 16; k++) {
            vf2 eb; eb.x = ear[k]; eb.y = ear[k];
            e01 += eb * W01[k];            // -> v_pk_fma_f32
            e23 += eb * W23[k];
        }
        vf2 h01, h23;
        h01.x = bf2f(hv.x); h01.y = bf2f(hv.y);
        h23.x = bf2f(hv.z); h23.y = bf2f(hv.w);
        vf2 att2; att2.x = att; att2.y = att;
        vf2 v01 = (h01 + e01) * att2;
        vf2 v23 = (h23 + e23) * att2;
        if (!valid) { v01 = ninf2; v23 = ninf2; }
        a01 = vmax2(a01, v01);
        a23 = vmax2(a23, v23);
    }
    // combine the 4 groups (xor lanes 16, 32)
    #pragma unroll
    for (int off = 16; off <= 32; off <<= 1) {
        a01.x = fmaxf(a01.x, __shfl_xor(a01.x, off));
        a01.y = fmaxf(a01.y, __shfl_xor(a01.y, off));
        a23.x = fmaxf(a23.x, __shfl_xor(a23.x, off));
        a23.y = fmaxf(a23.y, __shfl_xor(a23.y, off));
    }

    if (g == 0) {
        float4 bl = *(const float4*)(b + 4 * cl);
        float o0 = a01.x + bl.x, o1 = a01.y + bl.y;
        float o2 = a23.x + bl.z, o3 = a23.y + bl.w;
        o0 = (o0 >= 0.f) ? o0 : 0.01f * o0;
        o1 = (o1 >= 0.f) ? o1 : 0.01f * o1;
        o2 = (o2 >= 0.f) ? o2 : 0.01f * o2;
        o3 = (o3 >= 0.f) ? o3 : 0.01f * o3;
        size_t oidx = (size_t)d * D + 4 * cl;
        if (L2) {
            *(float4*)((float*)outv + oidx) = make_float4(o0, o1, o2, o3);
        } else {
            ushort4 ov = {f2bf(o0), f2bf(o1), f2bf(o2), f2bf(o3)};
            *(ushort4*)((unsigned short*)outv + oidx) = ov;
        }
    }
}

extern "C" void kernel_launch(void* const* d_in, const int* in_sizes, int n_in,
                              void* d_out, int out_size, void* d_ws, size_t ws_size,
                              hipStream_t stream) {
    // reference dtypes are all float32 (+ int32 edge_index)
    const float* X   = (const float*)d_in[0];
    const int*   eix = (const int*)d_in[1];
    const float* ea  = (const float*)d_in[2];
    const float* W1  = (const float*)d_in[3];
    const float* We1 = (const float*)d_in[4];
    const float* as1 = (const float*)d_in[5];
    const float* ad1 = (const float*)d_in[6];
    const float* ae1 = (const float*)d_in[7];
    const float* b1  = (const float*)d_in[8];
    const float* W2  = (const float*)d_in[9];
    const float* We2 = (const float*)d_in[10];
    const float* as2 = (const float*)d_in[11];
    const float* ad2 = (const float*)d_in[12];
    const float* ae2 = (const float*)d_in[13];
    const float* b2  = (const float*)d_in[14];

    const int* src = eix;
    const int* dst = eix + EE;

    // workspace carve — total ~39.4 MB
    char* w = (char*)d_ws;
    int4* recs = (int4*)w;               w += (size_t)EE * 16;         // 25.6 MB
    unsigned short* hA = (unsigned short*)w; w += (size_t)NN * D * 2;  // 6.4 MB (h1)
    unsigned short* hB = (unsigned short*)w; w += (size_t)NN * D * 2;  // 6.4 MB (c1 -> h2 in-place)
    float* hs = (float*)w;               w += (size_t)NN * 4;
    float* hd = (float*)w;               w += (size_t)NN * 4;
    int* counts = (int*)w;               w += (size_t)NN * 4;
    int* offsets = (int*)w;              w += (size_t)NN * 4;
    int* cursor = (int*)w;               w += (size_t)NN * 4;
    int* bsum = (int*)w;                 w += 256 * 4;

    const int nchunks = (NN + 255) / 256;   // 196

    hipMemsetAsync(counts, 0, (size_t)NN * 4, stream);
    k_hist<<<EE / 256, 256, 0, stream>>>(dst, counts);
    k_scanA<<<nchunks, 256, 0, stream>>>(counts, bsum);
    k_scanB<<<1, 256, 0, stream>>>(bsum, nchunks);
    k_scanC<<<nchunks, 256, 0, stream>>>(counts, bsum, offsets, cursor);
    k_scatter<<<EE / 256, 256, 0, stream>>>(src, dst, ea, We1, ae1, We2, ae2, cursor, recs);

    // layer 1
    k_gemm<0><<<1024, 256, 0, stream>>>(X, W1, as1, ad1, hA, hs, hd);
    k_gat<0><<<NN / 4, 256, 0, stream>>>(recs, offsets, counts, hs, hd, hA, ea, We1, b1, hB);
    // layer 2
    k_gemm<1><<<1024, 256, 0, stream>>>(hB, W2, as2, ad2, hB, hs, hd);   // in-place
    k_gat<1><<<NN / 4, 256, 0, stream>>>(recs, offsets, counts, hs, hd, hB, ea, We2, b2,
                                         (float*)d_out);
}

// Round 7
// 683.222 us; speedup vs baseline: 1.0893x; 1.0084x over previous
//
#include <hip/hip_runtime.h>
#include <cstdint>
#include <cstddef>

#define NN 50000
#define EE 1600000
#define D  64
#define DE 16

typedef __attribute__((ext_vector_type(2))) float vf2;

__device__ __forceinline__ float bf2f(unsigned short u) {
    return __uint_as_float(((unsigned)u) << 16);
}
__device__ __forceinline__ unsigned short f2bf(float f) {
    unsigned u = __float_as_uint(f);
    unsigned r = u + 0x7FFFu + ((u >> 16) & 1u);   // RNE
    return (unsigned short)(r >> 16);
}
__device__ __forceinline__ vf2 vmax2(vf2 a, vf2 b) {
    vf2 r; r.x = fmaxf(a.x, b.x); r.y = fmaxf(a.y, b.y); return r;
}

// ---------------- histogram of dst
__global__ __launch_bounds__(256) void k_hist(const int* dst, int* counts) {
    int e = blockIdx.x * 256 + threadIdx.x;
    if (e < EE) atomicAdd(&counts[dst[e]], 1);
}

// ---------------- 3-kernel exclusive scan over counts (chunks of 256)
__global__ __launch_bounds__(256) void k_scanA(const int* counts, int* bsum) {
    __shared__ int tmp[256];
    int t = threadIdx.x, i = blockIdx.x * 256 + t;
    tmp[t] = (i < NN) ? counts[i] : 0;
    __syncthreads();
    for (int off = 128; off; off >>= 1) {
        if (t < off) tmp[t] += tmp[t + off];
        __syncthreads();
    }
    if (t == 0) bsum[blockIdx.x] = tmp[0];
}

__global__ __launch_bounds__(256) void k_scanB(int* bsum, int nchunks) {
    __shared__ int tmp[256];
    int t = threadIdx.x;
    int v = (t < nchunks) ? bsum[t] : 0;
    tmp[t] = v; __syncthreads();
    for (int off = 1; off < 256; off <<= 1) {
        int x = (t >= off) ? tmp[t - off] : 0;
        __syncthreads();
        tmp[t] += x;
        __syncthreads();
    }
    if (t < nchunks) bsum[t] = tmp[t] - v;   // exclusive
}

__global__ __launch_bounds__(256) void k_scanC(const int* counts, const int* bsumex,
                                               int* offsets, int* cursor) {
    __shared__ int tmp[256];
    int t = threadIdx.x, i = blockIdx.x * 256 + t;
    int v = (i < NN) ? counts[i] : 0;
    tmp[t] = v; __syncthreads();
    for (int off = 1; off < 256; off <<= 1) {
        int x = (t >= off) ? tmp[t - off] : 0;
        __syncthreads();
        tmp[t] += x;
        __syncthreads();
    }
    int excl = tmp[t] - v + bsumex[blockIdx.x];
    if (i < NN) { offsets[i] = excl; cursor[i] = excl; }
}

// ---------------- scatter edges into dst-sorted AoS records {src, eid, ee1, ee2}
// wae = We@ae (both layers) recomputed per block (fused former k_wae dispatch)
__global__ __launch_bounds__(256) void k_scatter(const int* src, const int* dst,
                                                 const float* ea,
                                                 const float* We1, const float* ae1,
                                                 const float* We2, const float* ae2,
                                                 int* cursor, int4* recs) {
    __shared__ float wsh[32];
    int t = threadIdx.x;
    if (t < 32) {
        const float* We = (t < 16) ? We1 : We2;
        const float* ae = (t < 16) ? ae1 : ae2;
        int k = t & 15;
        float acc = 0.f;
        #pragma unroll
        for (int c = 0; c < 64; c++) acc += We[k * 64 + c] * ae[c];
        wsh[t] = acc;
    }
    __syncthreads();
    float w1r[16], w2r[16];
    #pragma unroll
    for (int j = 0; j < 16; j++) { w1r[j] = wsh[j]; w2r[j] = wsh[16 + j]; }

    int e = blockIdx.x * 256 + t;
    if (e >= EE) return;
    int d = dst[e];
    const float4* rp = (const float4*)(ea + (size_t)e * DE);
    float4 q0 = rp[0], q1 = rp[1], q2 = rp[2], q3 = rp[3];
    float ev[16] = {q0.x, q0.y, q0.z, q0.w, q1.x, q1.y, q1.z, q1.w,
                    q2.x, q2.y, q2.z, q2.w, q3.x, q3.y, q3.z, q3.w};
    float e1 = 0.f, e2 = 0.f;
    #pragma unroll
    for (int j = 0; j < 16; j++) {
        e1 += ev[j] * w1r[j];
        e2 += ev[j] * w2r[j];
    }
    int pos = atomicAdd(&cursor[d], 1);
    recs[pos] = make_int4(src[e], e, __float_as_int(e1), __float_as_int(e2));
}

// ---------------- per-layer: h = x@W, hs = h@a_s, hd = h@a_d
// W column in registers (64 VGPR/lane): __launch_bounds__(256,4) -> 128-VGPR budget
// so Wcol actually stays register-resident (at default the allocator targeted 8 waves
// and spilled it). IN_BF16: layer2 reads bf16 intermediate (in-place safe per-row).
template<int IN_BF16>
__global__ __launch_bounds__(256, 4) void k_gemm(const void* xin, const float* W,
                                                 const float* a_s, const float* a_d,
                                                 unsigned short* h, float* hs, float* hd) {
    int t = threadIdx.x, lane = t & 63;
    int wid0 = blockIdx.x * 4 + (t >> 6);        // 4096 waves total
    float Wcol[64];
    #pragma unroll
    for (int k = 0; k < 64; k++) Wcol[k] = W[k * 64 + lane];
    float asl = a_s[lane], adl = a_d[lane];
    for (int n0 = wid0; n0 < NN; n0 += 4096) {
        int n = __builtin_amdgcn_readfirstlane(n0);   // wave-uniform row address
        float acc = 0.f;
        if (IN_BF16) {
            const uint4* xr = (const uint4*)((const unsigned short*)xin + (size_t)n * 64);
            #pragma unroll
            for (int q = 0; q < 8; q++) {
                uint4 u = xr[q];
                unsigned uu[4] = {u.x, u.y, u.z, u.w};
                #pragma unroll
                for (int j = 0; j < 4; j++) {
                    acc += bf2f((unsigned short)(uu[j] & 0xFFFFu)) * Wcol[q * 8 + 2 * j];
                    acc += bf2f((unsigned short)(uu[j] >> 16))     * Wcol[q * 8 + 2 * j + 1];
                }
            }
        } else {
            const float4* xr = (const float4*)((const float*)xin + (size_t)n * 64);
            #pragma unroll
            for (int q = 0; q < 16; q++) {
                float4 u = xr[q];
                acc += u.x * Wcol[4 * q]     + u.y * Wcol[4 * q + 1]
                     + u.z * Wcol[4 * q + 2] + u.w * Wcol[4 * q + 3];
            }
        }
        h[(size_t)n * 64 + lane] = f2bf(acc);
        float ps = acc * asl, pd = acc * adl;
        #pragma unroll
        for (int off = 32; off; off >>= 1) {
            ps += __shfl_xor(ps, off);
            pd += __shfl_xor(pd, off);
        }
        if (lane == 0) { hs[n] = ps; hd[n] = pd; }
    }
}

// ---------------- fused per-node GAT: online-softmax, att cached in LDS,
// channel-max aggregate with packed-f32 math, bias+act.
// wave = one node. pass2: 4 groups x 16 lanes, one edge/group/iter, 4 ch/lane.
// __launch_bounds__(256,4): 128-VGPR budget so WelR (64 regs) stays resident —
// at default the allocator chose 60 VGPRs (8-wave target) and spilled/reloaded We
// every iteration, which was the real limiter (R6: pk-math cut VALU 52->46% with
// zero duration change; runtime occupancy only 39% anyway).
#define ATT_CAP 128
template<int L2>   // L2: selects ee field; fp32 output
__global__ __launch_bounds__(256, 4) void k_gat(const int4* recs, const int* offsets,
                                                const int* counts,
                                                const float* hs, const float* hd,
                                                const unsigned short* h, const float* ea,
                                                const float* We, const float* b, void* outv) {
    __shared__ float attl[4][ATT_CAP];
    int t = threadIdx.x, lane = t & 63, wv = t >> 6;
    int g = lane >> 4, cl = lane & 15;

    // register-resident We[k][4cl .. 4cl+3], packed as float2 pairs for v_pk_fma_f32
    vf2 W01[16], W23[16];
    #pragma unroll
    for (int k = 0; k < 16; k++) {
        float4 w = *(const float4*)(We + k * 64 + 4 * cl);
        W01[k].x = w.x; W01[k].y = w.y;
        W23[k].x = w.z; W23[k].y = w.w;
    }

    int d = blockIdx.x * 4 + wv;           // grid is exactly NN/4
    int start = offsets[d];
    int deg = counts[d];

    if (deg == 0) {                        // isfinite -> 0, then bias + act
        if (g == 0) {
            float4 bl = *(const float4*)(b + 4 * cl);
            float o0 = (bl.x >= 0.f) ? bl.x : 0.01f * bl.x;
            float o1 = (bl.y >= 0.f) ? bl.y : 0.01f * bl.y;
            float o2 = (bl.z >= 0.f) ? bl.z : 0.01f * bl.z;
            float o3 = (bl.w >= 0.f) ? bl.w : 0.01f * bl.w;
            size_t oidx = (size_t)d * D + 4 * cl;
            if (L2) *(float4*)((float*)outv + oidx) = make_float4(o0, o1, o2, o3);
            else {
                ushort4 ov = {f2bf(o0), f2bf(o1), f2bf(o2), f2bf(o3)};
                *(ushort4*)((unsigned short*)outv + oidx) = ov;
            }
        }
        return;
    }

    float hdv = hd[d];

    // pass 1: online softmax over logits (lane = edge); cache logits in LDS
    float m = -__builtin_inff();
    float s = 0.f;
    for (int i = lane; i < deg; i += 64) {
        int4 r = recs[start + i];
        float ee = __int_as_float(L2 ? r.w : r.z);
        float lg = hs[r.x] + hdv + ee;
        lg = (lg >= 0.f) ? lg : 0.2f * lg;
        if (i < ATT_CAP) attl[wv][i] = lg;
        float mn = fmaxf(m, lg);
        s = ((m == mn) ? s : s * __expf(m - mn)) + __expf(lg - mn);
        m = mn;
    }
    #pragma unroll
    for (int off = 32; off; off >>= 1) {
        float m2 = __shfl_xor(m, off);
        float s2 = __shfl_xor(s, off);
        float mn = fmaxf(m, m2);
        float sa = (m == mn) ? s : s * __expf(m - mn);
        float sb = (m2 == mn) ? s2 : s2 * __expf(m2 - mn);
        s = sa + sb;
        m = mn;
    }
    float invs = 1.0f / fmaxf(s, 1e-16f);

    // fixup: logits -> final attention weights in LDS (same wave: no barrier needed)
    int capdeg = min(deg, ATT_CAP);
    for (int i = lane; i < capdeg; i += 64)
        attl[wv][i] = __expf(attl[wv][i] - m) * invs;

    // pass 2: 4 edges/iter (one per 16-lane group), 4 channels per lane, packed f32
    vf2 ninf2; ninf2.x = -__builtin_inff(); ninf2.y = -__builtin_inff();
    vf2 a01 = ninf2, a23 = ninf2;
    bool cached = (deg <= ATT_CAP);        // wave-uniform
    for (int i = 0; i < deg; i += 4) {
        int j = i + g;
        bool valid = (j < deg);
        int jc = valid ? j : 0;
        int4 r = recs[start + jc];
        float att;
        if (cached) {
            att = attl[wv][jc];            // 16-lane broadcast read
        } else {
            float ee = __int_as_float(L2 ? r.w : r.z);
            float lg = hs[r.x] + hdv + ee;
            lg = (lg >= 0.f) ? lg : 0.2f * lg;
            att = __expf(lg - m) * invs;
        }
        const float4* ep = (const float4*)(ea + (size_t)r.y * DE);
        float4 q0 = ep[0], q1 = ep[1], q2 = ep[2], q3 = ep[3];
        ushort4 hv = *(const ushort4*)(h + (size_t)r.x * D + 4 * cl);

        float ear[16] = {q0.x, q0.y, q0.z, q0.w, q1.x, q1.y, q1.z, q1.w,
                         q2.x, q2.y, q2.z, q2.w, q3.x, q3.y, q3.z, q3.w};
        vf2 e01 = {0.f, 0.f}, e23 = {0.f, 0.f};
        #pragma unroll
        for (int k = 0; k < 16; k++) {
            vf2 eb; eb.x = ear[k]; eb.y = ear[k];
            e01 += eb * W01[k];            // -> v_pk_fma_f32
            e23 += eb * W23[k];
        }
        vf2 h01, h23;
        h01.x = bf2f(hv.x); h01.y = bf2f(hv.y);
        h23.x = bf2f(hv.z); h23.y = bf2f(hv.w);
        vf2 att2; att2.x = att; att2.y = att;
        vf2 v01 = (h01 + e01) * att2;
        vf2 v23 = (h23 + e23) * att2;
        if (!valid) { v01 = ninf2; v23 = ninf2; }
        a01 = vmax2(a01, v01);
        a23 = vmax2(a23, v23);
    }
    // combine the 4 groups (xor lanes 16, 32)
    #pragma unroll
    for (int off = 16; off <= 32; off <<= 1) {
        a01.x = fmaxf(a01.x, __shfl_xor(a01.x, off));
        a01.y = fmaxf(a01.y, __shfl_xor(a01.y, off));
        a23.x = fmaxf(a23.x, __shfl_xor(a23.x, off));
        a23.y = fmaxf(a23.y, __shfl_xor(a23.y, off));
    }

    if (g == 0) {
        float4 bl = *(const float4*)(b + 4 * cl);
        float o0 = a01.x + bl.x, o1 = a01.y + bl.y;
        float o2 = a23.x + bl.z, o3 = a23.y + bl.w;
        o0 = (o0 >= 0.f) ? o0 : 0.01f * o0;
        o1 = (o1 >= 0.f) ? o1 : 0.01f * o1;
        o2 = (o2 >= 0.f) ? o2 : 0.01f * o2;
        o3 = (o3 >= 0.f) ? o3 : 0.01f * o3;
        size_t oidx = (size_t)d * D + 4 * cl;
        if (L2) {
            *(float4*)((float*)outv + oidx) = make_float4(o0, o1, o2, o3);
        } else {
            ushort4 ov = {f2bf(o0), f2bf(o1), f2bf(o2), f2bf(o3)};
            *(ushort4*)((unsigned short*)outv + oidx) = ov;
        }
    }
}

extern "C" void kernel_launch(void* const* d_in, const int* in_sizes, int n_in,
                              void* d_out, int out_size, void* d_ws, size_t ws_size,
                              hipStream_t stream) {
    // reference dtypes are all float32 (+ int32 edge_index)
    const float* X   = (const float*)d_in[0];
    const int*   eix = (const int*)d_in[1];
    const float* ea  = (const float*)d_in[2];
    const float* W1  = (const float*)d_in[3];
    const float* We1 = (const float*)d_in[4];
    const float* as1 = (const float*)d_in[5];
    const float* ad1 = (const float*)d_in[6];
    const float* ae1 = (const float*)d_in[7];
    const float* b1  = (const float*)d_in[8];
    const float* W2  = (const float*)d_in[9];
    const float* We2 = (const float*)d_in[10];
    const float* as2 = (const float*)d_in[11];
    const float* ad2 = (const float*)d_in[12];
    const float* ae2 = (const float*)d_in[13];
    const float* b2  = (const float*)d_in[14];

    const int* src = eix;
    const int* dst = eix + EE;

    // workspace carve — total ~39.4 MB
    char* w = (char*)d_ws;
    int4* recs = (int4*)w;               w += (size_t)EE * 16;         // 25.6 MB
    unsigned short* hA = (unsigned short*)w; w += (size_t)NN * D * 2;  // 6.4 MB (h1)
    unsigned short* hB = (unsigned short*)w; w += (size_t)NN * D * 2;  // 6.4 MB (c1 -> h2 in-place)
    float* hs = (float*)w;               w += (size_t)NN * 4;
    float* hd = (float*)w;               w += (size_t)NN * 4;
    int* counts = (int*)w;               w += (size_t)NN * 4;
    int* offsets = (int*)w;              w += (size_t)NN * 4;
    int* cursor = (int*)w;               w += (size_t)NN * 4;
    int* bsum = (int*)w;                 w += 256 * 4;

    const int nchunks = (NN + 255) / 256;   // 196

    hipMemsetAsync(counts, 0, (size_t)NN * 4, stream);
    k_hist<<<EE / 256, 256, 0, stream>>>(dst, counts);
    k_scanA<<<nchunks, 256, 0, stream>>>(counts, bsum);
    k_scanB<<<1, 256, 0, stream>>>(bsum, nchunks);
    k_scanC<<<nchunks, 256, 0, stream>>>(counts, bsum, offsets, cursor);
    k_scatter<<<EE / 256, 256, 0, stream>>>(src, dst, ea, We1, ae1, We2, ae2, cursor, recs);

    // layer 1
    k_gemm<0><<<1024, 256, 0, stream>>>(X, W1, as1, ad1, hA, hs, hd);
    k_gat<0><<<NN / 4, 256, 0, stream>>>(recs, offsets, counts, hs, hd, hA, ea, We1, b1, hB);
    // layer 2
    k_gemm<1><<<1024, 256, 0, stream>>>(hB, W2, as2, ad2, hB, hs, hd);   // in-place
    k_gat<1><<<NN / 4, 256, 0, stream>>>(recs, offsets, counts, hs, hd, hB, ea, We2, b2,
                                         (float*)d_out);
}